// Round 7
// baseline (1525.482 us; speedup 1.0000x reference)
//
#include <hip/hip_runtime.h>

// HDC encoder = row gather: out[i, :] = vocab[tokens[i], :]
// N_TOKENS = 8192, DIMENSIONS = 10000, VOCAB = 32000, fp32.
// Memory-bound copy: ~618 MB compulsory HBM traffic -> ~100 us floor.
//
// Round 6 probe (resubmitted after broker timeout): one block per row,
// 10-deep load batch then 10 nontemporal stores -> 40 KB read burst /
// 40 KB write burst per block, fewer read/write turnarounds, 10
// outstanding global_load_dwordx4/lane.

typedef float f32x4 __attribute__((ext_vector_type(4)));

#define HDC_DIMS 10000
#define HDC_VEC4 (HDC_DIMS / 4)   // 2500 f32x4 per row
// 2500 = 9*256 + 196: 9 full strides of 256 threads + a 196-thread tail.

__global__ __launch_bounds__(256) void HDCEncoder_gather_kernel(
    const int* __restrict__ tokens,
    const f32x4* __restrict__ vocab,
    f32x4* __restrict__ out,
    int n_tokens)
{
    const int row = blockIdx.x;
    if (row >= n_tokens) return;
    const int tok = tokens[row];   // block-uniform -> scalar load
    const f32x4* __restrict__ src = vocab + (size_t)tok * HDC_VEC4;
    f32x4* __restrict__ dst       = out   + (size_t)row * HDC_VEC4;

    const int t = threadIdx.x;
    f32x4 v[10];
    #pragma unroll
    for (int k = 0; k < 9; ++k)
        v[k] = src[t + 256 * k];
    const bool tail = (t < HDC_VEC4 - 9 * 256);   // 196-thread tail
    if (tail)
        v[9] = src[t + 2304];
    #pragma unroll
    for (int k = 0; k < 9; ++k)
        __builtin_nontemporal_store(v[k], &dst[t + 256 * k]);
    if (tail)
        __builtin_nontemporal_store(v[9], &dst[t + 2304]);
}

extern "C" void kernel_launch(void* const* d_in, const int* in_sizes, int n_in,
                              void* d_out, int out_size, void* d_ws, size_t ws_size,
                              hipStream_t stream)
{
    const int* tokens   = (const int*)d_in[0];     // int32 tokens [N_TOKENS]
    const f32x4* vocab  = (const f32x4*)d_in[1];   // fp32 vocab [VOCAB, DIMS]
    f32x4* out          = (f32x4*)d_out;           // fp32 out [N_TOKENS, DIMS]
    const int n_tokens  = in_sizes[0];

    dim3 grid(n_tokens);
    dim3 block(256);
    HDCEncoder_gather_kernel<<<grid, block, 0, stream>>>(tokens, vocab, out, n_tokens);
}